// Round 2
// baseline (1208.110 us; speedup 1.0000x reference)
//
#include <hip/hip_runtime.h>
#include <math.h>

#define NPIX  4096
#define NC    2049          // NPIX/2 + 1
#define NVIS  500000
#define NTAPS 36
#define FFT_N 4096
#define FFT_T 256           // threads per FFT block
#define LOG2N 12

// ---------------------------------------------------------------------------
// Twiddle table: tw[k] = exp(-2*pi*i*k/4096), k = 0..2047 (computed in double)
// ---------------------------------------------------------------------------
__global__ void init_twiddles(float2* tw) {
    int k = blockIdx.x * blockDim.x + threadIdx.x;
    if (k < FFT_N / 2) {
        double ang = -2.0 * M_PI * (double)k / (double)FFT_N;
        tw[k] = make_float2((float)cos(ang), (float)sin(ang));
    }
}

// ---------------------------------------------------------------------------
// In-place 4096-point complex FFT in LDS. 256 threads cooperate.
// Classic bit-reverse + iterative radix-2 DIT. Twiddles from global table
// (16 KB, L1/L2-resident).
// ---------------------------------------------------------------------------
__device__ __forceinline__ void fft4096_lds(float* sre, float* sim,
                                            const float2* __restrict__ tw,
                                            int t) {
    // bit-reverse permutation (12 bits); one thread per swap pair
    #pragma unroll
    for (int it = 0; it < FFT_N / FFT_T; ++it) {
        int e = t + it * FFT_T;
        int r = (int)(__brev((unsigned)e) >> (32 - LOG2N));
        if (r > e) {
            float a = sre[e], b = sre[r]; sre[e] = b; sre[r] = a;
            float c = sim[e], d = sim[r]; sim[e] = d; sim[r] = c;
        }
    }
    __syncthreads();

    for (int s = 1; s <= LOG2N; ++s) {
        int half   = 1 << (s - 1);
        int tshift = LOG2N - s;
        #pragma unroll
        for (int it = 0; it < (FFT_N / 2) / FFT_T; ++it) {   // 8 butterflies/thread
            int b    = t + it * FFT_T;
            int j    = b & (half - 1);
            int base = ((b >> (s - 1)) << s) + j;
            float2 w = tw[j << tshift];
            float ur = sre[base],        ui = sim[base];
            float xr = sre[base + half], xi = sim[base + half];
            float vr = xr * w.x - xi * w.y;
            float vi = xr * w.y + xi * w.x;
            sre[base]        = ur + vr;  sim[base]        = ui + vi;
            sre[base + half] = ur - vr;  sim[base + half] = ui - vi;
        }
        __syncthreads();
    }
}

// ---------------------------------------------------------------------------
// Pass A: per-row  (image * corrfun * scale) -> 4096-pt FFT -> keep 2049 bins
// Output planes: a_re/a_im [4096][2049]
// ---------------------------------------------------------------------------
__global__ __launch_bounds__(FFT_T) void row_fft(const float* __restrict__ img,
                                                 const float* __restrict__ cf,
                                                 const float2* __restrict__ tw,
                                                 float* __restrict__ out_re,
                                                 float* __restrict__ out_im,
                                                 float scale) {
    __shared__ __align__(16) float sre[FFT_N];
    __shared__ __align__(16) float sim[FFT_N];
    int row = blockIdx.x;
    int t   = threadIdx.x;

    const float4* ip4 = (const float4*)(img + (size_t)row * NPIX);
    const float4* cp4 = (const float4*)(cf  + (size_t)row * NPIX);
    #pragma unroll
    for (int it = 0; it < (FFT_N / 4) / FFT_T; ++it) {
        int k = t + it * FFT_T;
        float4 a = ip4[k];
        float4 b = cp4[k];
        ((float4*)sre)[k] = make_float4(a.x * b.x * scale, a.y * b.y * scale,
                                        a.z * b.z * scale, a.w * b.w * scale);
        ((float4*)sim)[k] = make_float4(0.f, 0.f, 0.f, 0.f);
    }
    __syncthreads();

    fft4096_lds(sre, sim, tw, t);

    size_t ro = (size_t)row * NC;
    for (int k = t; k < NC; k += FFT_T) {
        out_re[ro + k] = sre[k];
        out_im[ro + k] = sim[k];
    }
}

// ---------------------------------------------------------------------------
// Pass B: transpose [H][W] -> [W][H], both planes via blockIdx.z
// ---------------------------------------------------------------------------
#define TDIM 32
__global__ __launch_bounds__(256) void transpose_k(const float* __restrict__ in,
                                                   float* __restrict__ out,
                                                   int H, int W) {
    __shared__ float tile[TDIM][TDIM + 1];
    size_t plane = (size_t)H * W;
    const float* src = in  + blockIdx.z * plane;
    float*       dst = out + blockIdx.z * plane;

    int bx = blockIdx.x * TDIM;   // along W
    int by = blockIdx.y * TDIM;   // along H
    int tx = threadIdx.x;         // 0..31
    int ty = threadIdx.y;         // 0..7

    #pragma unroll
    for (int i = ty; i < TDIM; i += 8) {
        int x = bx + tx, y = by + i;
        if (x < W && y < H) tile[i][tx] = src[(size_t)y * W + x];
    }
    __syncthreads();
    #pragma unroll
    for (int i = ty; i < TDIM; i += 8) {
        int oy = bx + i;    // along W (out rows)
        int ox = by + tx;   // along H (out cols)
        if (oy < W && ox < H) dst[(size_t)oy * H + ox] = tile[tx][i];
    }
}

// ---------------------------------------------------------------------------
// Pass C: per (transposed) column FFT; layout stays transposed [2049][4096]
// ---------------------------------------------------------------------------
__global__ __launch_bounds__(FFT_T) void col_fft(const float* __restrict__ tre,
                                                 const float* __restrict__ tim,
                                                 const float2* __restrict__ tw,
                                                 float* __restrict__ ore,
                                                 float* __restrict__ oim) {
    __shared__ __align__(16) float sre[FFT_N];
    __shared__ __align__(16) float sim[FFT_N];
    int c = blockIdx.x;
    int t = threadIdx.x;
    size_t off = (size_t)c * FFT_N;

    const float4* r4 = (const float4*)(tre + off);
    const float4* i4 = (const float4*)(tim + off);
    #pragma unroll
    for (int it = 0; it < (FFT_N / 4) / FFT_T; ++it) {
        int k = t + it * FFT_T;
        ((float4*)sre)[k] = r4[k];
        ((float4*)sim)[k] = i4[k];
    }
    __syncthreads();

    fft4096_lds(sre, sim, tw, t);

    float4* or4 = (float4*)(ore + off);
    float4* oi4 = (float4*)(oim + off);
    #pragma unroll
    for (int it = 0; it < (FFT_N / 4) / FFT_T; ++it) {
        int k = t + it * FFT_T;
        or4[k] = ((float4*)sre)[k];
        oi4[k] = ((float4*)sim)[k];
    }
}

// ---------------------------------------------------------------------------
// Pass D: 36-tap sparse gather. Grid is in TRANSPOSED layout:
//   flat idx = r*2049 + c  ->  address c*4096 + r
// ---------------------------------------------------------------------------
__global__ __launch_bounds__(256) void gather_k(const float* __restrict__ Cre,
                                                const float* __restrict__ Cim,
                                                const int* __restrict__ cols,
                                                const float* __restrict__ vr,
                                                const float* __restrict__ vi,
                                                float* __restrict__ out) {
    int v = blockIdx.x * blockDim.x + threadIdx.x;
    if (v >= NVIS) return;
    size_t base = (size_t)v * NTAPS;
    float ar = 0.f, ai = 0.f;
    #pragma unroll
    for (int tp = 0; tp < NTAPS; ++tp) {
        int idx  = cols[base + tp];
        int r    = idx / NC;           // constant divisor -> magic multiply
        int c    = idx - r * NC;
        int addr = c * FFT_N + r;
        ar = fmaf(Cre[base + tp], vr[addr], ar);
        ai = fmaf(Cim[base + tp], vi[addr], ai);
    }
    out[v]        = ar;
    out[NVIS + v] = ai;
}

// ---------------------------------------------------------------------------
extern "C" void kernel_launch(void* const* d_in, const int* in_sizes, int n_in,
                              void* d_out, int out_size, void* d_ws, size_t ws_size,
                              hipStream_t stream) {
    const float* image   = (const float*)d_in[0];
    const float* corrfun = (const float*)d_in[1];
    const float* Cre     = (const float*)d_in[2];
    const float* Cim     = (const float*)d_in[3];
    const int*   cols    = (const int*)d_in[4];
    float*       out     = (float*)d_out;

    char*  ws    = (char*)d_ws;
    size_t plane = (size_t)NPIX * NC * sizeof(float);   // 33,570,816 B
    float*  a_re = (float*)(ws + 0 * plane);
    float*  a_im = (float*)(ws + 1 * plane);
    float*  t_re = (float*)(ws + 2 * plane);
    float*  t_im = (float*)(ws + 3 * plane);
    float2* tw   = (float2*)(ws + 4 * plane);           // 16 KB

    double dll   = 0.005 * (M_PI / (180.0 * 3600.0));
    float  scale = (float)(dll * dll);

    init_twiddles<<<(FFT_N / 2 + 255) / 256, 256, 0, stream>>>(tw);

    // A: row FFTs (real input), keep 2049 bins, layout [4096][2049]
    row_fft<<<NPIX, FFT_T, 0, stream>>>(image, corrfun, tw, a_re, a_im, scale);

    // B: transpose both planes -> [2049][4096]
    dim3 tb(TDIM, 8);
    dim3 tg((NC + TDIM - 1) / TDIM, (NPIX + TDIM - 1) / TDIM, 2);
    transpose_k<<<tg, tb, 0, stream>>>(a_re, t_re, NPIX, NC);

    // C: column FFTs (coalesced in transposed layout); write into a_* planes
    col_fft<<<NC, FFT_T, 0, stream>>>(t_re, t_im, tw, a_re, a_im);

    // D: sparse 36-tap gather from transposed grid
    gather_k<<<(NVIS + 255) / 256, 256, 0, stream>>>(Cre, Cim, cols, a_re, a_im, out);
}

// Round 4
// 758.914 us; speedup vs baseline: 1.5919x; 1.5919x over previous
//
#include <hip/hip_runtime.h>
#include <math.h>

#define NPIX  4096
#define NC    2049          // NPIX/2 + 1
#define NVIS  500000
#define NTAPS 36
#define FFT_N 4096
#define FFT_T 256

// 16-point DFT constants
#define C16_1 0.923879532511286756f   // cos(pi/8)
#define S16_1 0.382683432365089772f   // sin(pi/8)
#define RSQ2  0.707106781186547524f   // sqrt(2)/2

#define CMUL(ar,ai,br,bi) { float _tr = (ar)*(br) - (ai)*(bi); \
                            (ai) = (ar)*(bi) + (ai)*(br); (ar) = _tr; }
#define MULNEGI(ar,ai)    { float _t = (ar); (ar) = (ai); (ai) = -_t; }

// forward 4-pt DFT (W4 = -i), in place on 4 complex regs
#define DFT4(r0,i0,r1,i1,r2,i2,r3,i3) { \
  float tr02=(r0)+(r2), ti02=(i0)+(i2), dr02=(r0)-(r2), di02=(i0)-(i2); \
  float tr13=(r1)+(r3), ti13=(i1)+(i3), dr13=(r1)-(r3), di13=(i1)-(i3); \
  (r0)=tr02+tr13; (i0)=ti02+ti13; \
  (r1)=dr02+di13; (i1)=di02-dr13; \
  (r2)=tr02-tr13; (i2)=ti02-ti13; \
  (r3)=dr02-di13; (i3)=di02+dr13; }

// ---------------------------------------------------------------------------
// Twiddles: tw[k] = exp(-2*pi*i*k/4096), k = 0..4095
// ---------------------------------------------------------------------------
__global__ void init_twiddles(float2* tw) {
    int k = blockIdx.x * blockDim.x + threadIdx.x;
    if (k < FFT_N) {
        double ang = -2.0 * M_PI * (double)k / (double)FFT_N;
        tw[k] = make_float2((float)cos(ang), (float)sin(ang));
    }
}

// ---------------------------------------------------------------------------
// In-register 16-pt DFT (4x4 Cooley-Tukey). All indices compile-time.
// Input x[n] in regs [n]. Output X[k] lands in reg p = 4*(k&3) + (k>>2).
// ---------------------------------------------------------------------------
__device__ __forceinline__ void dft16(float xr[16], float xi[16]) {
    // layer A: DFT4 over m1 (stride 4) for each m2 -> A[q1][m2] at reg 4*q1+m2
    #pragma unroll
    for (int m2 = 0; m2 < 4; ++m2)
        DFT4(xr[m2],    xi[m2],    xr[4+m2],  xi[4+m2],
             xr[8+m2],  xi[8+m2],  xr[12+m2], xi[12+m2]);
    // layer B: twiddle W16^{m2*q1} on reg [4*q1+m2]
    CMUL(xr[5],  xi[5],   C16_1, -S16_1);   // W^1
    CMUL(xr[6],  xi[6],   RSQ2,  -RSQ2);    // W^2
    CMUL(xr[7],  xi[7],   S16_1, -C16_1);   // W^3
    CMUL(xr[9],  xi[9],   RSQ2,  -RSQ2);    // W^2
    MULNEGI(xr[10], xi[10]);                // W^4 = -i
    CMUL(xr[11], xi[11], -RSQ2,  -RSQ2);    // W^6
    CMUL(xr[13], xi[13],  S16_1, -C16_1);   // W^3
    CMUL(xr[14], xi[14], -RSQ2,  -RSQ2);    // W^6
    CMUL(xr[15], xi[15], -C16_1,  S16_1);   // W^9 = -W^1
    // layer C: DFT4 over m2 (stride 1) for each q1 -> X[q1+4q2] at reg 4*q1+q2
    #pragma unroll
    for (int q1 = 0; q1 < 4; ++q1)
        DFT4(xr[4*q1],   xi[4*q1],   xr[4*q1+1], xi[4*q1+1],
             xr[4*q1+2], xi[4*q1+2], xr[4*q1+3], xi[4*q1+3]);
}

// ---------------------------------------------------------------------------
// 4096-pt complex FFT: 3 phases of radix-16, 16 points/thread, 256 threads.
// z: LDS float2[4096] holding input in natural order (caller synced).
// Phase-3 result X[t + 256*k3] is written to dst (LDS or global).
// ---------------------------------------------------------------------------
__device__ __forceinline__ void fft4096_reg(float2* z, float2* dst,
                                            const float2* __restrict__ tw,
                                            int t) {
    float xr[16], xi[16];

    // ---- phase 1: t = 16*n2 + n3; DFT over n1 (stride 256). Conflict-free.
    #pragma unroll
    for (int n1 = 0; n1 < 16; ++n1) {
        float2 v = z[t + 256 * n1]; xr[n1] = v.x; xi[n1] = v.y;
    }
    dft16(xr, xi);
    {
        int n2 = t >> 4;
        #pragma unroll
        for (int k1 = 1; k1 < 16; ++k1) {
            int p = ((k1 & 3) << 2) | (k1 >> 2);
            float2 w = tw[(16 * n2 * k1) & 4095];
            CMUL(xr[p], xi[p], w.x, w.y);
        }
    }
    #pragma unroll
    for (int k1 = 0; k1 < 16; ++k1) {      // write A[k1] at 256*k1 + t (own set)
        int p = ((k1 & 3) << 2) | (k1 >> 2);
        z[t + 256 * k1] = make_float2(xr[p], xi[p]);
    }
    __syncthreads();

    // ---- phase 2: k1 = t>>4, n3 = t&15; DFT over n2 (stride 16). 4-way banked.
    {
        int k1 = t >> 4, n3 = t & 15;
        #pragma unroll
        for (int m = 0; m < 16; ++m) {
            float2 v = z[256 * k1 + 16 * m + n3]; xr[m] = v.x; xi[m] = v.y;
        }
        __syncthreads();                   // all reads done before relayout writes
        dft16(xr, xi);
        #pragma unroll
        for (int k2 = 0; k2 < 16; ++k2) {
            int p = ((k2 & 3) << 2) | (k2 >> 2);
            float2 w = tw[(n3 * (k1 + 16 * k2)) & 4095];
            CMUL(xr[p], xi[p], w.x, w.y);
            z[k1 + 16 * k2 + 256 * n3] = make_float2(xr[p], xi[p]);
        }
    }
    __syncthreads();

    // ---- phase 3: t = k1 + 16*k2; DFT over n3 (stride 256). Conflict-free.
    #pragma unroll
    for (int m = 0; m < 16; ++m) {
        float2 v = z[t + 256 * m]; xr[m] = v.x; xi[m] = v.y;
    }
    dft16(xr, xi);
    #pragma unroll
    for (int k3 = 0; k3 < 16; ++k3) {
        int p = ((k3 & 3) << 2) | (k3 >> 2);
        dst[t + 256 * k3] = make_float2(xr[p], xi[p]);   // X[t + 256*k3]
    }
}

// ---------------------------------------------------------------------------
// Pass A: rows 2b, 2b+1 packed as re/im of ONE complex FFT; unpack to
// rfft rows 2b and 2b+1 of A[4096][2049] (float2 interleaved).
// ---------------------------------------------------------------------------
__global__ __launch_bounds__(FFT_T) void rowpair_fft(const float* __restrict__ img,
                                                     const float* __restrict__ cf,
                                                     const float2* __restrict__ tw,
                                                     float2* __restrict__ aout,
                                                     float scale) {
    __shared__ float2 z[FFT_N];            // 32 KB
    int t  = threadIdx.x;
    int r0 = 2 * blockIdx.x;

    const float4* i0 = (const float4*)(img + (size_t)r0 * NPIX);
    const float4* c0 = (const float4*)(cf  + (size_t)r0 * NPIX);
    const float4* i1 = (const float4*)(img + (size_t)(r0 + 1) * NPIX);
    const float4* c1 = (const float4*)(cf  + (size_t)(r0 + 1) * NPIX);
    #pragma unroll
    for (int j = 0; j < 4; ++j) {
        int s = t + 256 * j;               // float4 slot
        float4 a0 = i0[s], b0 = c0[s], a1 = i1[s], b1 = c1[s];
        z[4*s+0] = make_float2(a0.x * b0.x * scale, a1.x * b1.x * scale);
        z[4*s+1] = make_float2(a0.y * b0.y * scale, a1.y * b1.y * scale);
        z[4*s+2] = make_float2(a0.z * b0.z * scale, a1.z * b1.z * scale);
        z[4*s+3] = make_float2(a0.w * b0.w * scale, a1.w * b1.w * scale);
    }
    __syncthreads();

    fft4096_reg(z, z, tw, t);
    __syncthreads();

    // unpack: Xeven(k) = (Z(k)+conj(Z(-k)))/2 ; Xodd(k) = -i/2 (Z(k)-conj(Z(-k)))
    size_t ro0 = (size_t)r0 * NC, ro1 = ro0 + NC;
    #pragma unroll
    for (int j = 0; j < 9; ++j) {
        int k = t + 256 * j;
        if (k <= 2048) {
            float2 zk = z[k];
            float2 zm = z[(FFT_N - k) & (FFT_N - 1)];
            aout[ro0 + k] = make_float2(0.5f * (zk.x + zm.x), 0.5f * (zk.y - zm.y));
            aout[ro1 + k] = make_float2(0.5f * (zk.y + zm.y), 0.5f * (zm.x - zk.x));
        }
    }
}

// ---------------------------------------------------------------------------
// Pass B: float2 transpose [4096][2049] -> [2049][4096]
// ---------------------------------------------------------------------------
#define TDIM 32
__global__ __launch_bounds__(256) void transpose2(const float2* __restrict__ in,
                                                  float2* __restrict__ out) {
    __shared__ float2 tile[TDIM][TDIM + 1];
    const int H = NPIX, W = NC;
    int bx = blockIdx.x * TDIM;            // along W (2049)
    int by = blockIdx.y * TDIM;            // along H (4096)
    int tx = threadIdx.x;                  // 0..31
    int ty = threadIdx.y;                  // 0..7

    #pragma unroll
    for (int i = ty; i < TDIM; i += 8) {
        int x = bx + tx, y = by + i;
        if (x < W) tile[i][tx] = in[(size_t)y * W + x];
    }
    __syncthreads();
    #pragma unroll
    for (int i = ty; i < TDIM; i += 8) {
        int oy = bx + i;                   // along W
        int ox = by + tx;                  // along H
        if (oy < W) out[(size_t)oy * H + ox] = tile[tx][i];
    }
}

// ---------------------------------------------------------------------------
// Pass C: complex 4096-pt FFT per transposed row (= image column); writes the
// final interleaved grid[c][r] directly from phase 3 (coalesced).
// ---------------------------------------------------------------------------
__global__ __launch_bounds__(FFT_T) void col_fft(const float2* __restrict__ tin,
                                                 const float2* __restrict__ tw,
                                                 float2* __restrict__ grid) {
    __shared__ float2 z[FFT_N];
    int t = threadIdx.x;
    size_t off = (size_t)blockIdx.x * FFT_N;

    const float4* s4 = (const float4*)(tin + off);   // 2 complex per float4
    #pragma unroll
    for (int j = 0; j < 8; ++j) {
        int s = t + 256 * j;
        float4 v = s4[s];
        z[2*s]   = make_float2(v.x, v.y);
        z[2*s+1] = make_float2(v.z, v.w);
    }
    __syncthreads();

    fft4096_reg(z, grid + off, tw, t);
}

// ---------------------------------------------------------------------------
// Pass D: 36-tap gather from interleaved transposed grid.
//   flat idx = r*2049 + c  ->  float2 at c*4096 + r  (ONE 8B load per tap)
// ---------------------------------------------------------------------------
__global__ __launch_bounds__(256) void gather_k(const float* __restrict__ Cre,
                                                const float* __restrict__ Cim,
                                                const int* __restrict__ cols,
                                                const float2* __restrict__ grid,
                                                float* __restrict__ out) {
    int v = blockIdx.x * blockDim.x + threadIdx.x;
    if (v >= NVIS) return;
    // 36 * 4B = 144B per row, 144 % 16 == 0 -> int4/float4 aligned
    const int4*   c4 = (const int4*)cols + (size_t)v * 9;
    const float4* r4 = (const float4*)Cre + (size_t)v * 9;
    const float4* m4 = (const float4*)Cim + (size_t)v * 9;
    float ar = 0.f, ai = 0.f;
    #pragma unroll
    for (int u = 0; u < 9; ++u) {
        int4   id = c4[u];
        float4 wr = r4[u];
        float4 wi = m4[u];
        {
            int row = id.x / NC, col = id.x - row * NC;
            float2 g = grid[(size_t)col * FFT_N + row];
            ar = fmaf(wr.x, g.x, ar); ai = fmaf(wi.x, g.y, ai);
        }
        {
            int row = id.y / NC, col = id.y - row * NC;
            float2 g = grid[(size_t)col * FFT_N + row];
            ar = fmaf(wr.y, g.x, ar); ai = fmaf(wi.y, g.y, ai);
        }
        {
            int row = id.z / NC, col = id.z - row * NC;
            float2 g = grid[(size_t)col * FFT_N + row];
            ar = fmaf(wr.z, g.x, ar); ai = fmaf(wi.z, g.y, ai);
        }
        {
            int row = id.w / NC, col = id.w - row * NC;
            float2 g = grid[(size_t)col * FFT_N + row];
            ar = fmaf(wr.w, g.x, ar); ai = fmaf(wi.w, g.y, ai);
        }
    }
    out[v]        = ar;
    out[NVIS + v] = ai;
}

// ---------------------------------------------------------------------------
extern "C" void kernel_launch(void* const* d_in, const int* in_sizes, int n_in,
                              void* d_out, int out_size, void* d_ws, size_t ws_size,
                              hipStream_t stream) {
    const float* image   = (const float*)d_in[0];
    const float* corrfun = (const float*)d_in[1];
    const float* Cre     = (const float*)d_in[2];
    const float* Cim     = (const float*)d_in[3];
    const int*   cols    = (const int*)d_in[4];
    float*       out     = (float*)d_out;

    char*  ws     = (char*)d_ws;
    size_t plane2 = (size_t)NPIX * NC * sizeof(float2);   // 67,141,632 B
    float2* A    = (float2*)(ws + 0);           // pass A out; reused as final grid
    float2* T    = (float2*)(ws + plane2);      // transposed [2049][4096]
    float2* tw   = (float2*)(ws + 2 * plane2);  // 32 KB twiddles

    double dll   = 0.005 * (M_PI / (180.0 * 3600.0));
    float  scale = (float)(dll * dll);

    init_twiddles<<<FFT_N / 256, 256, 0, stream>>>(tw);

    // A: 2048 packed real-pair row FFTs -> A[4096][2049] float2
    rowpair_fft<<<NPIX / 2, FFT_T, 0, stream>>>(image, corrfun, tw, A, scale);

    // B: transpose -> T[2049][4096]
    dim3 tb(TDIM, 8);
    dim3 tg((NC + TDIM - 1) / TDIM, NPIX / TDIM);
    transpose2<<<tg, tb, 0, stream>>>(A, T);

    // C: 2049 column FFTs; final grid written into A (interleaved, transposed)
    col_fft<<<NC, FFT_T, 0, stream>>>(T, tw, A);

    // D: sparse 36-tap gather
    gather_k<<<(NVIS + 255) / 256, 256, 0, stream>>>(Cre, Cim, cols, A, out);
}